// Round 8
// baseline (610.587 us; speedup 1.0000x reference)
//
#include <hip/hip_runtime.h>

#define TOPK 32

typedef float vfloat4 __attribute__((ext_vector_type(4)));

// ---------------------------------------------------------------------------
// Software grid barrier (cooperative launch is unavailable in this harness).
// cnt/flag zeroed by hipMemsetAsync before each launch. Device-scope atomics +
// threadfence give cross-XCD visibility of plain stores made before arrival.
// ---------------------------------------------------------------------------
__device__ __forceinline__ void gbar(int* cnt, int* flag, int nblocks) {
    __syncthreads();
    if (threadIdx.x == 0) {
        __threadfence();
        int arrived = __hip_atomic_fetch_add(cnt, 1, __ATOMIC_ACQ_REL,
                                             __HIP_MEMORY_SCOPE_AGENT);
        if (arrived == nblocks - 1) {
            __hip_atomic_store(flag, 1, __ATOMIC_RELEASE,
                               __HIP_MEMORY_SCOPE_AGENT);
        } else {
            while (__hip_atomic_load(flag, __ATOMIC_ACQUIRE,
                                     __HIP_MEMORY_SCOPE_AGENT) == 0)
                __builtin_amdgcn_s_sleep(4);
        }
        __threadfence();
    }
    __syncthreads();
}

// ---------------------------------------------------------------------------
// Persistent fused kernel, 1024 blocks x 256 threads (4 blocks/CU guaranteed
// by __launch_bounds__(256,4): VGPR<=128, LDS 16.5KB -> all co-resident).
// Phases:
//  A: histogram pos -> counts (global atomics; counts pre-zeroed)
//  B: d2[row] = dot(base[row,:], W[b,:]) for referenced rows only (~63%)
//  C: blocks 0..B-1: gather+relu -> exact top-32 (ties->lower idx) -> mean;
//     blocks B..: stream mixed=base for count==0 rows (needs no mean) --
//     hides the serial top-k under copy traffic.
//  D: mixed = base + counts*mean*W for referenced rows.
// ---------------------------------------------------------------------------
__global__ __launch_bounds__(256, 4)
void fused_kernel(const float* __restrict__ base,
                  const int* __restrict__ pos,
                  const float* __restrict__ bw,
                  float* __restrict__ out_mixed,
                  float* __restrict__ out_detect,
                  float* __restrict__ out_nontopk,
                  int* __restrict__ bar,
                  int* __restrict__ counts,
                  float* __restrict__ d2,
                  float* __restrict__ meanv,
                  int B, int S, int H, int nblocks) {
    __shared__ float vals[4096];          // S floats (S==4096)

    const int t = threadIdx.x;
    const int nrows = B * S;
    const int gtid = blockIdx.x * 256 + t;
    const int nthr = nblocks * 256;
    const int n4 = H >> 2;                // 512

    // ---- Phase A: histogram ---------------------------------------------
    for (int i = gtid; i < nrows; i += nthr) {
        int b = i / S;
        atomicAdd(&counts[b * S + pos[i]], 1);
    }
    gbar(&bar[0], &bar[8], nblocks);

    // ---- Phase B: dots for referenced rows ------------------------------
    {
        const int w = gtid >> 6, lane = t & 63, nw = nthr >> 6;
        for (int row = w; row < nrows; row += nw) {
            if (counts[row] == 0) continue;
            const float4* rp = (const float4*)(base + (size_t)row * H);
            const float4* wp = (const float4*)(bw + (size_t)(row / S) * H);
            float acc = 0.f;
            #pragma unroll 8
            for (int i = lane; i < n4; i += 64) {
                float4 v = rp[i];
                float4 wv = wp[i];
                acc += v.x * wv.x + v.y * wv.y + v.z * wv.z + v.w * wv.w;
            }
            #pragma unroll
            for (int off = 32; off > 0; off >>= 1)
                acc += __shfl_down(acc, off, 64);
            if (lane == 0) d2[row] = acc;
        }
    }
    gbar(&bar[1], &bar[9], nblocks);

    // ---- Phase C: top-k (blocks 0..B-1)  ||  copy count==0 rows ---------
    if (blockIdx.x < B) {
        int b = blockIdx.x;
        for (int i = t; i < S; i += 256) {
            // d2[p] valid: p appears in pos -> counts[p]>0 -> dot computed
            float v = fmaxf(d2[(size_t)b * S + pos[(size_t)b * S + i]], 0.f);
            vals[i] = v;
            out_detect[(size_t)b * S + i] = v;
        }
        __syncthreads();
        if (t < 64) {                     // single wave: barrier-free top-k
            int lane = t;
            float sum = 0.f;
            for (int it = 0; it < TOPK; ++it) {
                float lv = -INFINITY;
                int   li = 0x7fffffff;
                for (int c = lane * 4; c < S; c += 256) {
                    float4 v = *(const float4*)&vals[c];
                    if (v.x > lv) { lv = v.x; li = c; }
                    if (v.y > lv) { lv = v.y; li = c + 1; }
                    if (v.z > lv) { lv = v.z; li = c + 2; }
                    if (v.w > lv) { lv = v.w; li = c + 3; }
                }
                #pragma unroll
                for (int off = 32; off > 0; off >>= 1) {
                    float ov = __shfl_down(lv, off, 64);
                    int   oi = __shfl_down(li, off, 64);
                    if (ov > lv || (ov == lv && oi < li)) { lv = ov; li = oi; }
                }
                lv = __shfl(lv, 0, 64);
                li = __shfl(li, 0, 64);
                sum += lv;
                if (lane == 0) vals[li] = -INFINITY;  // wave-synchronous
            }
            if (lane == 0) meanv[b] = sum / (float)TOPK;
        }
        __syncthreads();
        for (int i = t; i < S; i += 256) {
            float v = vals[i];
            out_nontopk[(size_t)b * S + i] = (v == -INFINITY) ? 0.f : v;
        }
    } else {
        for (int row = blockIdx.x - B; row < nrows; row += nblocks - B) {
            if (counts[row] != 0) continue;
            const float4* bp = (const float4*)(base + (size_t)row * H);
            vfloat4*      op = (vfloat4*)(out_mixed + (size_t)row * H);
            #pragma unroll 2
            for (int i = t; i < n4; i += 256) {
                float4 v = bp[i];
                vfloat4 o;
                o.x = v.x; o.y = v.y; o.z = v.z; o.w = v.w;
                __builtin_nontemporal_store(o, &op[i]);
            }
        }
    }
    gbar(&bar[2], &bar[10], nblocks);

    // ---- Phase D: mix for referenced rows -------------------------------
    for (int row = blockIdx.x; row < nrows; row += nblocks) {
        int c = counts[row];
        if (c == 0) continue;
        int b = row / S;
        float scale = (float)c * meanv[b];
        const float4* bp = (const float4*)(base + (size_t)row * H);
        const float4* wp = (const float4*)(bw + (size_t)b * H);
        vfloat4*      op = (vfloat4*)(out_mixed + (size_t)row * H);
        #pragma unroll 2
        for (int i = t; i < n4; i += 256) {
            float4 v = bp[i];
            float4 w = wp[i];
            vfloat4 o;
            o.x = v.x + scale * w.x;
            o.y = v.y + scale * w.y;
            o.z = v.z + scale * w.z;
            o.w = v.w + scale * w.w;
            __builtin_nontemporal_store(o, &op[i]);
        }
    }
}

// ---------------------------------------------------------------------------
extern "C" void kernel_launch(void* const* d_in, const int* in_sizes, int n_in,
                              void* d_out, int out_size, void* d_ws, size_t ws_size,
                              hipStream_t stream) {
    const float* base = (const float*)d_in[0];
    const int*   pos  = (const int*)d_in[1];
    const float* bw   = (const float*)d_in[2];

    long n0 = in_sizes[0];               // B*S*H
    long n1 = in_sizes[1];               // B*S
    long n2 = in_sizes[2];               // B*H
    int H = (int)(n0 / n1);
    int B = (int)(n2 / H);
    int S = (int)(n1 / B);

    float* out_mixed   = (float*)d_out;
    float* out_detect  = out_mixed + (size_t)B * S * H;
    float* out_nontopk = out_detect + (size_t)B * S;

    // ws layout: [bar:16 ints][counts: B*S ints][d2: B*S floats][meanv: B]
    int*   bar    = (int*)d_ws;
    int*   counts = bar + 16;
    float* d2     = (float*)(counts + (size_t)B * S);
    float* meanv  = d2 + (size_t)B * S;

    int nblocks = 1024;                  // 4 blocks/CU x 256 CUs, co-resident

    // zero barrier state + counts (graph-safe; re-zeroed on every replay)
    hipMemsetAsync(d_ws, 0, (16 + (size_t)B * S) * sizeof(int), stream);

    fused_kernel<<<nblocks, 256, 0, stream>>>(
        base, pos, bw, out_mixed, out_detect, out_nontopk,
        bar, counts, d2, meanv, B, S, H, nblocks);
}

// Round 9
// 166.298 us; speedup vs baseline: 3.6716x; 3.6716x over previous
//
#include <hip/hip_runtime.h>

#define TOPK 32

typedef float vfloat4 __attribute__((ext_vector_type(4)));

// ---------------------------------------------------------------------------
// K0: per-batch histogram of pos -> counts. B blocks, LDS atomics. ~4us.
// Writes every counts entry (no memset needed).
// ---------------------------------------------------------------------------
__global__ void hist_kernel(const int* __restrict__ pos,
                            int* __restrict__ counts,
                            int S) {
    extern __shared__ int cnt[];          // S ints
    int b = blockIdx.x;
    int t = threadIdx.x;
    for (int i = t; i < S; i += 256) cnt[i] = 0;
    __syncthreads();
    for (int i = t; i < S; i += 256)
        atomicAdd(&cnt[pos[(size_t)b * S + i]], 1);
    __syncthreads();
    for (int i = t; i < S; i += 256)
        counts[(size_t)b * S + i] = cnt[i];
}

// ---------------------------------------------------------------------------
// K1: one wave per row; dot ONLY for referenced rows (count>0, ~63%).
//   d2[row] = dot(base[row,:], W[b,:])
// Normal loads (may leave the 162MB of touched rows L3-resident for K3).
// ---------------------------------------------------------------------------
__global__ void dot_kernel(const float* __restrict__ base,
                           const float* __restrict__ bw,
                           const int* __restrict__ counts,
                           float* __restrict__ d2,
                           int S, int H) {
    int wid  = (blockIdx.x * blockDim.x + threadIdx.x) >> 6;  // row = b*S + p
    int lane = threadIdx.x & 63;
    if (counts[wid] == 0) return;
    int b = wid / S;

    const float4* row = (const float4*)(base + (size_t)wid * H);
    const float4* w4  = (const float4*)(bw + (size_t)b * H);
    int n4 = H >> 2;                      // 512

    float acc = 0.f;
    #pragma unroll 8
    for (int i = lane; i < n4; i += 64) {
        float4 v = row[i];
        float4 w = w4[i];
        acc += v.x * w.x + v.y * w.y + v.z * w.z + v.w * w.w;
    }
    #pragma unroll
    for (int off = 32; off > 0; off >>= 1)
        acc += __shfl_down(acc, off, 64);

    if (lane == 0) d2[wid] = acc;
}

// ---------------------------------------------------------------------------
// K2: blocks 0..B-1: per-batch gather d2 -> detect, exact top-32 by a single
//     wave (ties -> lower index), nontopk, mean.
//     blocks B.. : stream-copy mixed=base for count==0 rows (~37%) with NT
//     loads/stores -- this traffic hides the serial top-k instead of idling
//     248 CUs, and doesn't pollute L3 (keep dot's rows resident for K3).
// ---------------------------------------------------------------------------
__global__ void topk_copy_kernel(const float* __restrict__ d2,
                                 const int* __restrict__ pos,
                                 const int* __restrict__ counts,
                                 const float* __restrict__ base,
                                 float* __restrict__ mixed,
                                 float* __restrict__ detect,
                                 float* __restrict__ nontopk,
                                 float* __restrict__ meanv,
                                 int B, int S, int H, int nblocks) {
    __shared__ float smem[8192];          // dvals[S] + vals[S], S==4096
    int t = threadIdx.x;

    if (blockIdx.x < B) {
        float* dvals = smem;
        float* vals  = smem + S;
        int b = blockIdx.x;

        for (int i = t; i < S; i += 256)
            dvals[i] = d2[(size_t)b * S + i];
        __syncthreads();
        for (int i = t; i < S; i += 256) {
            float v = fmaxf(dvals[pos[(size_t)b * S + i]], 0.f);
            vals[i] = v;
            detect[(size_t)b * S + i] = v;
        }
        __syncthreads();

        if (t < 64) {                     // single wave: barrier-free top-k
            int lane = t;
            float sum = 0.f;
            for (int it = 0; it < TOPK; ++it) {
                float lv = -INFINITY;
                int   li = 0x7fffffff;
                for (int c = lane * 4; c < S; c += 256) {
                    float4 v = *(const float4*)&vals[c];
                    if (v.x > lv) { lv = v.x; li = c; }
                    if (v.y > lv) { lv = v.y; li = c + 1; }
                    if (v.z > lv) { lv = v.z; li = c + 2; }
                    if (v.w > lv) { lv = v.w; li = c + 3; }
                }
                #pragma unroll
                for (int off = 32; off > 0; off >>= 1) {
                    float ov = __shfl_down(lv, off, 64);
                    int   oi = __shfl_down(li, off, 64);
                    if (ov > lv || (ov == lv && oi < li)) { lv = ov; li = oi; }
                }
                lv = __shfl(lv, 0, 64);
                li = __shfl(li, 0, 64);
                sum += lv;
                if (lane == 0) vals[li] = -INFINITY;  // wave-synchronous
            }
            if (lane == 0) meanv[b] = sum / (float)TOPK;
        }
        __syncthreads();
        for (int i = t; i < S; i += 256) {
            float v = vals[i];
            nontopk[(size_t)b * S + i] = (v == -INFINITY) ? 0.f : v;
        }
    } else {
        int nrows = B * S;
        int ncopy = nblocks - B;
        int n4 = H >> 2;                  // 512
        for (int row = blockIdx.x - B; row < nrows; row += ncopy) {
            if (counts[row] != 0) continue;
            const vfloat4* bp = (const vfloat4*)(base + (size_t)row * H);
            vfloat4*       op = (vfloat4*)(mixed + (size_t)row * H);
            #pragma unroll 2
            for (int i = t; i < n4; i += 256) {
                vfloat4 v = __builtin_nontemporal_load(&bp[i]);
                __builtin_nontemporal_store(v, &op[i]);
            }
        }
    }
}

// ---------------------------------------------------------------------------
// K3: 4 consecutive rows per block; ONLY count>0 rows (~63%):
//   mixed[b,p,:] = base[b,p,:] + counts[b,p]*mean[b]*W[b,:]
// Normal loads (L3 may still hold rows from K1); NT stores for output.
// ---------------------------------------------------------------------------
__global__ void mix_kernel(const float* __restrict__ base,
                           const float* __restrict__ bw,
                           const int* __restrict__ counts,
                           const float* __restrict__ meanv,
                           float* __restrict__ mixed,
                           int S, int H) {
    int r0 = blockIdx.x << 2;
    int b  = r0 / S;
    const float4* w4 = (const float4*)(bw + (size_t)b * H);
    float mb = meanv[b];
    int n4 = H >> 2;                      // 512

    for (int r = r0; r < r0 + 4; ++r) {
        int c = counts[r];
        if (c == 0) continue;             // copied by K2
        float scale = (float)c * mb;
        const float4* b4 = (const float4*)(base + (size_t)r * H);
        vfloat4*      o4 = (vfloat4*)(mixed + (size_t)r * H);
        #pragma unroll 2
        for (int i = threadIdx.x; i < n4; i += blockDim.x) {
            float4 v = b4[i];
            float4 w = w4[i];
            vfloat4 o;
            o.x = v.x + scale * w.x;
            o.y = v.y + scale * w.y;
            o.z = v.z + scale * w.z;
            o.w = v.w + scale * w.w;
            __builtin_nontemporal_store(o, &o4[i]);
        }
    }
}

// ---------------------------------------------------------------------------
extern "C" void kernel_launch(void* const* d_in, const int* in_sizes, int n_in,
                              void* d_out, int out_size, void* d_ws, size_t ws_size,
                              hipStream_t stream) {
    const float* base = (const float*)d_in[0];
    const int*   pos  = (const int*)d_in[1];
    const float* bw   = (const float*)d_in[2];

    long n0 = in_sizes[0];               // B*S*H
    long n1 = in_sizes[1];               // B*S
    long n2 = in_sizes[2];               // B*H
    int H = (int)(n0 / n1);
    int B = (int)(n2 / H);
    int S = (int)(n1 / B);

    float* out_mixed   = (float*)d_out;
    float* out_detect  = out_mixed + (size_t)B * S * H;
    float* out_nontopk = out_detect + (size_t)B * S;

    int*   counts = (int*)d_ws;
    float* d2     = (float*)((char*)d_ws + (size_t)B * S * sizeof(int));
    float* meanv  = (float*)((char*)d_ws + 2 * (size_t)B * S * sizeof(int));

    int nrows = B * S;
    int nk2   = B + 1024;                // 8 topk blocks + 1024 copy blocks

    hist_kernel<<<B, 256, (size_t)S * sizeof(int), stream>>>(pos, counts, S);
    dot_kernel<<<nrows / 4, 256, 0, stream>>>(base, bw, counts, d2, S, H);
    topk_copy_kernel<<<nk2, 256, 0, stream>>>(
        d2, pos, counts, base, out_mixed, out_detect, out_nontopk, meanv,
        B, S, H, nk2);
    mix_kernel<<<nrows / 4, 256, 0, stream>>>(base, bw, counts, meanv, out_mixed, S, H);
}